// Round 3
// baseline (50.707 us; speedup 1.0000x reference)
//
#include <hip/hip_runtime.h>
#include <hip/hip_bf16.h>

// RWKV TimeMix forward, MI355X.
// prep(vectorized mix+cast) -> gemm3 (pipelined gload_lds, exp epi on k)
//   -> windowed scan (float4/thread) -> gemm_out (pipelined).
// GEMM: 64x64 tile, K_STEP=64, 2 LDS buffers, counted vmcnt(4), raw s_barrier.
// LDS swizzle: linear dest for global_load_lds; source col pre-swizzled by
// (l&7)^(l>>3) and ds_read XORs slot^(row&7) — same involution both sides.

#define T_LEN 767
#define C_DIM 768
#define SZ (768 * 768)
#define R_CHUNK 4

typedef __attribute__((ext_vector_type(4))) float f32x4;
typedef __attribute__((ext_vector_type(8))) short s16x8;
typedef __attribute__((ext_vector_type(4))) short s16x4;

__device__ __forceinline__ short bfbits(float f) {
    __hip_bfloat16 h = __float2bfloat16(f);
    return *reinterpret_cast<short*>(&h);
}

__device__ __forceinline__ void gload16(const void* g, void* l) {
    __builtin_amdgcn_global_load_lds(
        (const __attribute__((address_space(1))) void*)g,
        (__attribute__((address_space(3))) void*)l, 16, 0, 0);
}

// grid (576, 5), 256 thr. y==0: time-mix+cast (4 elems/thr). y 1..4: W cast.
__global__ __launch_bounds__(256) void prep_kernel(
    const float* __restrict__ x, const float* __restrict__ tmk,
    const float* __restrict__ tmv, const float* __restrict__ tmr,
    const float* __restrict__ Wk, const float* __restrict__ Wv,
    const float* __restrict__ Wr, const float* __restrict__ Wo,
    __hip_bfloat16* __restrict__ xkvr, __hip_bfloat16* __restrict__ Wb,
    __hip_bfloat16* __restrict__ rwkv)
{
    int base = (blockIdx.x * 256 + threadIdx.x) * 4;
    int job = blockIdx.y;
    if (job != 0) {
        const float* src = (job == 1) ? Wk : (job == 2) ? Wv : (job == 3) ? Wr : Wo;
        f32x4 w = *(const f32x4*)(src + base);
        s16x4 o;
        #pragma unroll
        for (int j = 0; j < 4; ++j) o[j] = bfbits(w[j]);
        *(s16x4*)(Wb + (size_t)(job - 1) * SZ + base) = o;
        return;
    }
    int t = base / C_DIM, c = base - t * C_DIM;
    if (t == T_LEN) {
        s16x4 z = {0, 0, 0, 0};
        *(s16x4*)(xkvr + base) = z;
        *(s16x4*)(xkvr + SZ + base) = z;
        *(s16x4*)(xkvr + 2 * SZ + base) = z;
        *(s16x4*)(rwkv + base) = z;   // padded row for final GEMM
        return;
    }
    f32x4 xc = *(const f32x4*)(x + base);
    f32x4 xp = {0, 0, 0, 0};
    if (t) xp = *(const f32x4*)(x + base - C_DIM);
    f32x4 mk = *(const f32x4*)(tmk + c);
    f32x4 mv = *(const f32x4*)(tmv + c);
    f32x4 mr = *(const f32x4*)(tmr + c);
    s16x4 ok, ov, orr;
    #pragma unroll
    for (int j = 0; j < 4; ++j) {
        ok[j]  = bfbits(xc[j] * mk[j] + xp[j] * (1.f - mk[j]));
        ov[j]  = bfbits(xc[j] * mv[j] + xp[j] * (1.f - mv[j]));
        orr[j] = bfbits(xc[j] * mr[j] + xp[j] * (1.f - mr[j]));
    }
    *(s16x4*)(xkvr + base) = ok;
    *(s16x4*)(xkvr + SZ + base) = ov;
    *(s16x4*)(xkvr + 2 * SZ + base) = orr;
}

// C[bi*64.., bj*64..] = A * B^T, K=768, K_STEP=64, pipelined.
// epi: 0 plain, 1 exp(min(v,60)), 2 rows<767 only.
__device__ __forceinline__ void gemm_nt64(const __hip_bfloat16* __restrict__ A,
                                          const __hip_bfloat16* __restrict__ B,
                                          float* __restrict__ C,
                                          int bi, int bj, int epi)
{
    __shared__ __hip_bfloat16 lds[2][2][64 * 64];   // [buf][A/B], 32 KiB
    const int tid = threadIdx.x, lane = tid & 63, w = tid >> 6;
    const int wr = w >> 1, wc = w & 1;               // 2x2 waves, 32x32 each
    const int l3 = lane >> 3, l7 = lane & 7;
    const int swz = (l7 ^ l3) * 8;                   // pre-swizzled source col
    const __hip_bfloat16* gA = A + (size_t)(bi * 64 + w * 16 + l3) * C_DIM + swz;
    const __hip_bfloat16* gB = B + (size_t)(bj * 64 + w * 16 + l3) * C_DIM + swz;
    const int frow = lane & 15, g = lane >> 4, r7 = frow & 7;

    f32x4 acc[2][2] = {};

#define STAGE(buf, k0)                                                \
    do {                                                              \
        gload16(gA + (k0),               &lds[buf][0][w * 1024]);     \
        gload16(gA + (k0) + 8 * C_DIM,   &lds[buf][0][w * 1024 + 512]); \
        gload16(gB + (k0),               &lds[buf][1][w * 1024]);     \
        gload16(gB + (k0) + 8 * C_DIM,   &lds[buf][1][w * 1024 + 512]); \
    } while (0)

    STAGE(0, 0);
    for (int t = 0; t < 12; ++t) {
        if (t < 11) {
            STAGE((t + 1) & 1, (t + 1) * 64);
            asm volatile("s_waitcnt vmcnt(4)" ::: "memory");  // t's loads done
        } else {
            asm volatile("s_waitcnt vmcnt(0)" ::: "memory");
        }
        asm volatile("s_barrier" ::: "memory");               // buf[t] valid
        const __hip_bfloat16* la = &lds[t & 1][0][0];
        const __hip_bfloat16* lb = &lds[t & 1][1][0];
        s16x8 af[2][2], bfv[2][2];
        #pragma unroll
        for (int h = 0; h < 2; ++h) {
            #pragma unroll
            for (int m = 0; m < 2; ++m) {
                int ra = wr * 32 + m * 16 + frow;
                int rb = wc * 32 + m * 16 + frow;
                int so = ((h * 4 + g) ^ r7) * 8;
                af[h][m]  = *(const s16x8*)(la + ra * 64 + so);
                bfv[h][m] = *(const s16x8*)(lb + rb * 64 + so);
            }
        }
        #pragma unroll
        for (int h = 0; h < 2; ++h)
            #pragma unroll
            for (int m = 0; m < 2; ++m)
                #pragma unroll
                for (int n = 0; n < 2; ++n)
                    acc[m][n] = __builtin_amdgcn_mfma_f32_16x16x32_bf16(
                        af[h][m], bfv[h][n], acc[m][n], 0, 0, 0);
        asm volatile("s_barrier" ::: "memory");  // all reads done; buf reusable
    }
#undef STAGE

    // C/D layout: col = lane&15, row = (lane>>4)*4 + j   [m89-verified]
    int rbase = bi * 64 + wr * 32 + (lane >> 4) * 4;
    int cbase = bj * 64 + wc * 32 + (lane & 15);
    #pragma unroll
    for (int m = 0; m < 2; ++m) {
        #pragma unroll
        for (int n = 0; n < 2; ++n) {
            #pragma unroll
            for (int j = 0; j < 4; ++j) {
                int row = rbase + m * 16 + j;
                int col = cbase + n * 16;
                float v = acc[m][n][j];
                if (epi == 1) v = __expf(fminf(v, 60.f));
                if (epi != 2 || row < T_LEN)
                    C[(size_t)row * C_DIM + col] = v;
            }
        }
    }
}

__global__ __launch_bounds__(256) void gemm3_kernel(
    const __hip_bfloat16* __restrict__ xkvr,
    const __hip_bfloat16* __restrict__ Wb, float* __restrict__ kvr)
{
    int z = blockIdx.z;  // 0=k (exp epilogue), 1=v, 2=r
    gemm_nt64(xkvr + (size_t)z * SZ, Wb + (size_t)z * SZ, kvr + (size_t)z * SZ,
              blockIdx.x, blockIdx.y, z == 0 ? 1 : 0);
}

__global__ __launch_bounds__(256) void gemm_out_kernel(
    const __hip_bfloat16* __restrict__ rwkv,
    const __hip_bfloat16* __restrict__ Wo_b, float* __restrict__ out)
{
    gemm_nt64(rwkv, Wo_b, out, blockIdx.x, blockIdx.y, 2);
}

// Windowed decay scan, 4 channels/thread via float4. dm^64 < 1e-45 -> exact.
// grid (3, 192), 64 threads.
__global__ __launch_bounds__(64) void scan_kernel(
    const float* __restrict__ kb, const float* __restrict__ vb,
    const float* __restrict__ rb, const float* __restrict__ td,
    const float* __restrict__ tf, __hip_bfloat16* __restrict__ rwkv)
{
    int d  = (blockIdx.x * 64 + threadIdx.x) * 4;
    int t0 = blockIdx.y * R_CHUNK;
    f32x4 dm, etf;
    {
        f32x4 tdv = *(const f32x4*)(td + d);
        f32x4 tfv = *(const f32x4*)(tf + d);
        #pragma unroll
        for (int j = 0; j < 4; ++j) {
            dm[j]  = __expf(-__expf(tdv[j]));
            etf[j] = __expf(tfv[j]);
        }
    }
    f32x4 a = {0, 0, 0, 0}, b = {0, 0, 0, 0};
    #pragma unroll 16
    for (int i = 64; i >= 1; --i) {
        int t = t0 - i;
        int tt = t < 0 ? 0 : t;
        f32x4 kk = *(const f32x4*)(kb + tt * C_DIM + d);
        f32x4 vv = *(const f32x4*)(vb + tt * C_DIM + d);
        if (t < 0) { f32x4 z = {0, 0, 0, 0}; kk = z; vv = z; }
        #pragma unroll
        for (int j = 0; j < 4; ++j) {
            a[j] = fmaf(dm[j], a[j], kk[j] * vv[j]);
            b[j] = fmaf(dm[j], b[j], kk[j]);
        }
    }
    int t1 = min(t0 + R_CHUNK, T_LEN);
    for (int t = t0; t < t1; ++t) {
        f32x4 kk = *(const f32x4*)(kb + t * C_DIM + d);
        f32x4 vv = *(const f32x4*)(vb + t * C_DIM + d);
        f32x4 rr = *(const f32x4*)(rb + t * C_DIM + d);
        s16x4 o;
        #pragma unroll
        for (int j = 0; j < 4; ++j) {
            float kv  = kk[j] * vv[j];
            float wkv = fmaf(etf[j], kv, a[j]);
            float wk  = fmaf(etf[j], kk[j], b[j]) + 1e-8f;
            float sig = 1.f / (1.f + __expf(-rr[j]));
            o[j] = bfbits(sig * wkv / wk);
            a[j] = fmaf(dm[j], a[j], kv);
            b[j] = fmaf(dm[j], b[j], kk[j]);
        }
        *(s16x4*)(rwkv + t * C_DIM + d) = o;
    }
}

extern "C" void kernel_launch(void* const* d_in, const int* in_sizes, int n_in,
                              void* d_out, int out_size, void* d_ws, size_t ws_size,
                              hipStream_t stream)
{
    const float* x   = (const float*)d_in[0];
    const float* td  = (const float*)d_in[1];
    const float* tf  = (const float*)d_in[2];
    const float* tmk = (const float*)d_in[3];
    const float* tmv = (const float*)d_in[4];
    const float* tmr = (const float*)d_in[5];
    const float* Wk  = (const float*)d_in[6];
    const float* Wv  = (const float*)d_in[7];
    const float* Wr  = (const float*)d_in[8];
    const float* Wo  = (const float*)d_in[9];
    float* out = (float*)d_out;

    char* ws = (char*)d_ws;
    __hip_bfloat16* xkvr = (__hip_bfloat16*)ws;
    __hip_bfloat16* Wb   = (__hip_bfloat16*)(ws + (size_t)3 * SZ * 2);
    float*          kvr  = (float*)(ws + (size_t)7 * SZ * 2);
    __hip_bfloat16* rwkv = (__hip_bfloat16*)(ws + (size_t)7 * SZ * 2 + (size_t)3 * SZ * 4);

    prep_kernel<<<dim3(SZ / 1024, 5), 256, 0, stream>>>(
        x, tmk, tmv, tmr, Wk, Wv, Wr, Wo, xkvr, Wb, rwkv);
    gemm3_kernel<<<dim3(12, 12, 3), 256, 0, stream>>>(xkvr, Wb, kvr);
    scan_kernel<<<dim3(3, 192), 64, 0, stream>>>(
        kvr, kvr + SZ, kvr + 2 * SZ, td, tf, rwkv);
    gemm_out_kernel<<<dim3(12, 12), 256, 0, stream>>>(rwkv, Wb + (size_t)3 * SZ, out);
}